// Round 6
// baseline (455.868 us; speedup 1.0000x reference)
//
#include <hip/hip_runtime.h>
#include <hip/hip_bf16.h>
#include <cstdint>
#include <cstddef>

// Dims (fixed by the problem)
#define N_INP 512
#define N_OUT 256
#define H 3
#define HD (H * N_OUT)       // 768
#define AGG_D (H * (N_INP + 1))  // 1539 logical (513 per head: 512 emb + 1 homogeneous)
#define HSTR 522             // per-head stride in bf16 agg (keeps 4B alignment, room for pad)
#define KP 1568              // padded K for MFMA GEMM (multiple of 32; 3*522=1566 <= 1568)
#define GEMM_NT (KP / 32)    // 49 k-steps

typedef __attribute__((ext_vector_type(8))) short short8;
typedef __attribute__((ext_vector_type(4))) float f32x4;

__device__ inline unsigned short f2bf(float x) {
    union { float f; unsigned u; } v; v.f = x;
    unsigned r = v.u + 0x7fffu + ((v.u >> 16) & 1u);  // RNE
    return (unsigned short)(r >> 16);
}
__device__ inline float bflo2f(unsigned u) {  // low 16 bits -> float
    union { unsigned u; float f; } v; v.u = u << 16; return v.f;
}
__device__ inline float bfhi2f(unsigned u) {  // high 16 bits -> float
    union { unsigned u; float f; } v; v.u = u & 0xffff0000u; return v.f;
}

// async global->LDS, 16B per lane. LDS dest is the wave-uniform base;
// HW writes lane i at base + i*16.
__device__ inline void glds16(const void* g, void* l) {
    __builtin_amdgcn_global_load_lds(
        (const __attribute__((address_space(1))) void*)g,
        (__attribute__((address_space(3))) void*)l, 16, 0, 0);
}

// ---------------------------------------------------------------------------
// small utility kernels
// ---------------------------------------------------------------------------

// wave-per-output: v_l[h][o] = sum_t Wsrc[o, h*256+t] * attn_l[h,t]  (v_r: Wdst/attn_r)
__global__ __launch_bounds__(256) void v_kernel(
    const float* __restrict__ Wsrc, const float* __restrict__ Wdst,
    const float* __restrict__ attn_l, const float* __restrict__ attn_r,
    float* __restrict__ v) {
    int wave = threadIdx.x >> 6, lane = threadIdx.x & 63;
    int idx = blockIdx.x * 4 + wave;
    if (idx >= 2 * H * N_INP) return;
    int which = idx / (H * N_INP);
    int r = idx % (H * N_INP);
    int h = r / N_INP, o = r % N_INP;
    const float* W = which ? Wdst : Wsrc;
    const float* at = which ? attn_r : attn_l;
    float s = 0.f;
#pragma unroll
    for (int i = 0; i < N_OUT / 64; ++i) {
        int t = lane + i * 64;
        s += W[(size_t)o * HD + h * N_OUT + t] * at[h * N_OUT + t];
    }
#pragma unroll
    for (int off = 32; off >= 1; off >>= 1) s += __shfl_xor(s, off, 64);
    if (lane == 0) v[idx] = s;
}

// wave-per-output: u (idx<3072) and ebias (idx in [3072,3078))
__global__ __launch_bounds__(256) void u_kernel(
    const float* __restrict__ Wapi, const float* __restrict__ Wfile,
    const float* __restrict__ bapi, const float* __restrict__ bfile,
    const float* __restrict__ v, float* __restrict__ u,
    float* __restrict__ ebias) {
    int wave = threadIdx.x >> 6, lane = threadIdx.x & 63;
    int idx = blockIdx.x * 4 + wave;
    if (idx < 2 * H * N_INP) {
        int which = idx / (H * N_INP);
        int r = idx % (H * N_INP);
        int h = r / N_INP, i = r % N_INP;
        const float* W = which ? Wfile : Wapi;
        const float* vv = v + which * (H * N_INP) + h * N_INP;
        float s = 0.f;
#pragma unroll
        for (int j = 0; j < N_INP / 64; ++j) {
            int o = lane + j * 64;
            s += W[(size_t)i * N_INP + o] * vv[o];
        }
#pragma unroll
        for (int off = 32; off >= 1; off >>= 1) s += __shfl_xor(s, off, 64);
        if (lane == 0) u[idx] = s;
    } else if (idx < 2 * H * N_INP + 6) {
        int k = idx - 2 * H * N_INP;
        int which = k / H, h = k % H;
        const float* b = which ? bfile : bapi;
        const float* vv = v + which * (H * N_INP) + h * N_INP;
        float s = 0.f;
#pragma unroll
        for (int j = 0; j < N_INP / 64; ++j) {
            int o = lane + j * 64;
            s += b[o] * vv[o];
        }
#pragma unroll
        for (int off = 32; off >= 1; off >>= 1) s += __shfl_xor(s, off, 64);
        if (lane == 0) ebias[k] = s;
    }
}

// merged attention-logit kernel over api (side 0) + file (side 1) nodes:
// el/er[n,h] = emb[n,:] . u[side,h,:] + ebias[side*3+h]; api side also writes
// bf16 emb copy. Also zeroes the CSR counts array (side job, saves a launch).
__global__ __launch_bounds__(256) void elr2_kernel(
    const float* __restrict__ embA, const float* __restrict__ embF,
    const float* __restrict__ u, const float* __restrict__ ebias,
    float* __restrict__ el, float* __restrict__ er,
    unsigned short* __restrict__ embB, int* __restrict__ counts,
    int nA, int nF) {
    __shared__ float su[2 * H * N_INP];   // 12 KB
    {   // counts zeroing side-job (independent of node work)
        int zi = blockIdx.x * 256 + threadIdx.x;
        if (zi < nF) counts[zi] = 0;
    }
    for (int i = threadIdx.x; i < 2 * H * N_INP; i += 256) su[i] = u[i];
    __syncthreads();
    int wave = threadIdx.x >> 6;
    int lane = threadIdx.x & 63;
    int node = blockIdx.x * 4 + wave;
    if (node >= nA + nF) return;
    int side = (node >= nA);
    int nn = side ? node - nA : node;
    const float* emb = side ? embF : embA;
    float* out = side ? (er + (size_t)nn * H) : (el + (size_t)nn * H);
    const float4* row = (const float4*)(emb + (size_t)nn * N_INP);
    float4 v0 = row[lane];        // cols lane*4 .. +3
    float4 v1 = row[64 + lane];   // cols 256+lane*4 .. +3
    int c0 = lane * 4, c1 = 256 + lane * 4;
    if (!side) {
        unsigned short* o = embB + (size_t)nn * N_INP;
        ushort4 p0, p1;
        p0.x = f2bf(v0.x); p0.y = f2bf(v0.y); p0.z = f2bf(v0.z); p0.w = f2bf(v0.w);
        p1.x = f2bf(v1.x); p1.y = f2bf(v1.y); p1.z = f2bf(v1.z); p1.w = f2bf(v1.w);
        *(ushort4*)(o + c0) = p0;
        *(ushort4*)(o + c1) = p1;
    }
    const float* ub = su + side * (H * N_INP);
    float d[H];
#pragma unroll
    for (int h = 0; h < H; ++h) {
        const float* uh = ub + h * N_INP;
        d[h] = v0.x * uh[c0] + v0.y * uh[c0 + 1] + v0.z * uh[c0 + 2] + v0.w * uh[c0 + 3]
             + v1.x * uh[c1] + v1.y * uh[c1 + 1] + v1.z * uh[c1 + 2] + v1.w * uh[c1 + 3];
#pragma unroll
        for (int off = 32; off >= 1; off >>= 1) d[h] += __shfl_xor(d[h], off, 64);
    }
    if (lane == 0) {
#pragma unroll
        for (int h = 0; h < H; ++h) out[h] = d[h] + ebias[side * 3 + h];
    }
}

__global__ void count_kernel(const int* __restrict__ dst, int* __restrict__ counts, int E) {
    int e = blockIdx.x * blockDim.x + threadIdx.x;
    if (e < E) atomicAdd(&counts[dst[e]], 1);
}

// single-block exclusive scan of counts -> offsets, cursor; offsets[n] = total
__global__ __launch_bounds__(1024) void scan_kernel(const int* __restrict__ counts,
                                                    int* __restrict__ offsets,
                                                    int* __restrict__ cursor, int n) {
    __shared__ int part[1024];
    int t = threadIdx.x;
    const int CH = (n + 1023) / 1024;
    int lo = t * CH, hi = min(lo + CH, n);
    int s = 0;
    for (int i = lo; i < hi; ++i) s += counts[i];
    part[t] = s;
    __syncthreads();
    for (int off = 1; off < 1024; off <<= 1) {
        int v = (t >= off) ? part[t - off] : 0;
        __syncthreads();
        part[t] += v;
        __syncthreads();
    }
    int base = (t == 0) ? 0 : part[t - 1];
    for (int i = lo; i < hi; ++i) {
        offsets[i] = base; cursor[i] = base;
        base += counts[i];
    }
    if (t == 1023) offsets[n] = part[1023];
}

__global__ void scatter_kernel(const int* __restrict__ src, const int* __restrict__ dst,
                               int* __restrict__ cursor, int* __restrict__ csr_src, int E) {
    int e = blockIdx.x * blockDim.x + threadIdx.x;
    if (e < E) {
        int slot = atomicAdd(&cursor[dst[e]], 1);
        csr_src[slot] = src[e];
    }
}

// one block (256 threads) per dst node: FUSED edge-softmax + aggregation.
// Phase 1/2: per-head max then exp-sum over incoming edges (el gather, 12B/edge).
// Phase 3: chunked gather of embB rows weighted by w = exp(e-m)/z.
// aggB[d, h*HSTR + 512] = (deg>0) ? 1 : 0 ; cols [513,HSTR) and [3*HSTR,KP) pad 0.
#define AGG_CH 512
__global__ __launch_bounds__(256) void agg_kernel(
    const int* __restrict__ offsets, const int* __restrict__ csr_src,
    const float* __restrict__ el, const float* __restrict__ er,
    const unsigned short* __restrict__ embB,
    unsigned short* __restrict__ aggB, int nd) {
    __shared__ int su[AGG_CH];
    __shared__ float sw0[AGG_CH], sw1[AGG_CH], sw2[AGG_CH];
    __shared__ float sred[12], sm[3], sz[3];
    int d = blockIdx.x;
    if (d >= nd) return;
    int tid = threadIdx.x, wave = tid >> 6, lane = tid & 63;
    int lo = offsets[d], hi = offsets[d + 1], cnt = hi - lo;
    float er0 = er[(size_t)d * H + 0], er1 = er[(size_t)d * H + 1], er2 = er[(size_t)d * H + 2];
    // ---- phase 1: per-head max over edges ----
    float p0 = -3.4e38f, p1 = -3.4e38f, p2 = -3.4e38f;
    for (int i = tid; i < cnt; i += 256) {
        int uu = csr_src[lo + i];
        float e0 = el[(size_t)uu * H + 0] + er0; e0 = e0 >= 0.f ? e0 : 0.2f * e0;
        float e1 = el[(size_t)uu * H + 1] + er1; e1 = e1 >= 0.f ? e1 : 0.2f * e1;
        float e2 = el[(size_t)uu * H + 2] + er2; e2 = e2 >= 0.f ? e2 : 0.2f * e2;
        p0 = fmaxf(p0, e0); p1 = fmaxf(p1, e1); p2 = fmaxf(p2, e2);
    }
#pragma unroll
    for (int off = 32; off >= 1; off >>= 1) {
        p0 = fmaxf(p0, __shfl_xor(p0, off, 64));
        p1 = fmaxf(p1, __shfl_xor(p1, off, 64));
        p2 = fmaxf(p2, __shfl_xor(p2, off, 64));
    }
    if (lane == 0) { sred[wave * 3 + 0] = p0; sred[wave * 3 + 1] = p1; sred[wave * 3 + 2] = p2; }
    __syncthreads();
    if (tid < 3) {
        float v = sred[tid];
        v = fmaxf(v, sred[3 + tid]); v = fmaxf(v, sred[6 + tid]); v = fmaxf(v, sred[9 + tid]);
        sm[tid] = v;
    }
    __syncthreads();
    float m0 = sm[0], m1 = sm[1], m2 = sm[2];
    // ---- phase 2: per-head exp-sum ----
    p0 = 0.f; p1 = 0.f; p2 = 0.f;
    for (int i = tid; i < cnt; i += 256) {
        int uu = csr_src[lo + i];
        float e0 = el[(size_t)uu * H + 0] + er0; e0 = e0 >= 0.f ? e0 : 0.2f * e0;
        float e1 = el[(size_t)uu * H + 1] + er1; e1 = e1 >= 0.f ? e1 : 0.2f * e1;
        float e2 = el[(size_t)uu * H + 2] + er2; e2 = e2 >= 0.f ? e2 : 0.2f * e2;
        p0 += expf(e0 - m0); p1 += expf(e1 - m1); p2 += expf(e2 - m2);
    }
#pragma unroll
    for (int off = 32; off >= 1; off >>= 1) {
        p0 += __shfl_xor(p0, off, 64);
        p1 += __shfl_xor(p1, off, 64);
        p2 += __shfl_xor(p2, off, 64);
    }
    if (lane == 0) { sred[wave * 3 + 0] = p0; sred[wave * 3 + 1] = p1; sred[wave * 3 + 2] = p2; }
    __syncthreads();
    if (tid < 3) sz[tid] = sred[tid] + sred[3 + tid] + sred[6 + tid] + sred[9 + tid];
    __syncthreads();
    float iz0 = 1.f / sz[0], iz1 = 1.f / sz[1], iz2 = 1.f / sz[2];
    // ---- phase 3: chunked weighted gather of embB ----
    const unsigned* ebdw = (const unsigned*)embB;   // 256 dwords per row
    float a00 = 0.f, a01 = 0.f, a10 = 0.f, a11 = 0.f, a20 = 0.f, a21 = 0.f;
    for (int baseE = lo; baseE < hi; baseE += AGG_CH) {
        int cc = min(hi - baseE, AGG_CH);
        for (int i = tid; i < cc; i += 256) {
            int uu = csr_src[baseE + i];
            su[i] = uu;
            float e0 = el[(size_t)uu * H + 0] + er0; e0 = e0 >= 0.f ? e0 : 0.2f * e0;
            float e1 = el[(size_t)uu * H + 1] + er1; e1 = e1 >= 0.f ? e1 : 0.2f * e1;
            float e2 = el[(size_t)uu * H + 2] + er2; e2 = e2 >= 0.f ? e2 : 0.2f * e2;
            sw0[i] = expf(e0 - m0) * iz0;
            sw1[i] = expf(e1 - m1) * iz1;
            sw2[i] = expf(e2 - m2) * iz2;
        }
        __syncthreads();
        int i = 0;
        for (; i + 4 <= cc; i += 4) {
            int u0 = su[i], u1 = su[i + 1], u2 = su[i + 2], u3 = su[i + 3];
            unsigned v0 = ebdw[((size_t)u0 << 8) + tid];
            unsigned v1 = ebdw[((size_t)u1 << 8) + tid];
            unsigned v2 = ebdw[((size_t)u2 << 8) + tid];
            unsigned v3 = ebdw[((size_t)u3 << 8) + tid];
            float w00 = sw0[i], w01 = sw1[i], w02 = sw2[i];
            float w10 = sw0[i+1], w11 = sw1[i+1], w12 = sw2[i+1];
            float w20 = sw0[i+2], w21 = sw1[i+2], w22 = sw2[i+2];
            float w30 = sw0[i+3], w31 = sw1[i+3], w32 = sw2[i+3];
            float x, y;
            x = bflo2f(v0); y = bfhi2f(v0);
            a00 += w00 * x; a01 += w00 * y; a10 += w01 * x; a11 += w01 * y; a20 += w02 * x; a21 += w02 * y;
            x = bflo2f(v1); y = bfhi2f(v1);
            a00 += w10 * x; a01 += w10 * y; a10 += w11 * x; a11 += w11 * y; a20 += w12 * x; a21 += w12 * y;
            x = bflo2f(v2); y = bfhi2f(v2);
            a00 += w20 * x; a01 += w20 * y; a10 += w21 * x; a11 += w21 * y; a20 += w22 * x; a21 += w22 * y;
            x = bflo2f(v3); y = bfhi2f(v3);
            a00 += w30 * x; a01 += w30 * y; a10 += w31 * x; a11 += w31 * y; a20 += w32 * x; a21 += w32 * y;
        }
        for (; i < cc; ++i) {
            int uu = su[i];
            unsigned v = ebdw[((size_t)uu << 8) + tid];
            float w0 = sw0[i], w1 = sw1[i], w2 = sw2[i];
            float x = bflo2f(v), y = bfhi2f(v);
            a00 += w0 * x; a01 += w0 * y;
            a10 += w1 * x; a11 += w1 * y;
            a20 += w2 * x; a21 += w2 * y;
        }
        __syncthreads();
    }
    int c = tid * 2;
    size_t base = (size_t)d * KP;
    *(unsigned*)(aggB + base + 0 * HSTR + c) = (unsigned)f2bf(a00) | ((unsigned)f2bf(a01) << 16);
    *(unsigned*)(aggB + base + 1 * HSTR + c) = (unsigned)f2bf(a10) | ((unsigned)f2bf(a11) << 16);
    *(unsigned*)(aggB + base + 2 * HSTR + c) = (unsigned)f2bf(a20) | ((unsigned)f2bf(a21) << 16);
    if (tid == 0) {
        unsigned short flag = (cnt > 0) ? (unsigned short)0x3f80 : (unsigned short)0; // bf16 1.0 / 0.0
#pragma unroll
        for (int h = 0; h < H; ++h) {
            aggB[base + h * HSTR + 512] = flag;
            for (int z = 513; z < HSTR; ++z) aggB[base + h * HSTR + z] = 0;
        }
        aggB[base + 3 * HSTR + 0] = 0;
        aggB[base + 3 * HSTR + 1] = 0;
    }
}

// weight GEMM with MLP + TLP: C[M,256] = A[M,K] @ B[K,256], batched over blockIdx.z.
template <int K>
__global__ __launch_bounds__(256) void wgemm(
    const float* __restrict__ A, int lda, size_t sAz,
    const float* __restrict__ B, int ldb, size_t sBz,
    float* __restrict__ C, int ldc, size_t sCz, int M) {
    A += blockIdx.z * sAz; B += blockIdx.z * sBz; C += blockIdx.z * sCz;
    __shared__ float sA[8 * K];
    __shared__ float red[8 * 256];   // 8 rows x (4 ksub x 64 cols)
    int tid = threadIdx.x;
    int r0 = blockIdx.x * 8;
    int bn = blockIdx.y * 64;
    for (int i = tid; i < 8 * K; i += 256) {
        int r = i / K, k = i % K;
        sA[i] = A[(size_t)(r0 + r) * lda + k];
    }
    __syncthreads();
    int cl = tid & 63, ks = tid >> 6;
    int col = bn + cl;
    const int KC = K / 4;
    float acc[8] = {};
    for (int k0 = ks * KC; k0 < ks * KC + KC; k0 += 8) {
        float b[8];
#pragma unroll
        for (int j = 0; j < 8; ++j) b[j] = B[(size_t)(k0 + j) * ldb + col];
#pragma unroll
        for (int j = 0; j < 8; ++j) {
            float bb = b[j];
#pragma unroll
            for (int i = 0; i < 8; ++i) acc[i] += sA[i * K + k0 + j] * bb;
        }
    }
#pragma unroll
    for (int i = 0; i < 8; ++i) red[i * 256 + ks * 64 + cl] = acc[i];
    __syncthreads();
    for (int t = tid; t < 512; t += 256) {
        int i = t >> 6, c = t & 63;
        float s = red[i * 256 + c] + red[i * 256 + 64 + c]
                + red[i * 256 + 128 + c] + red[i * 256 + 192 + c];
        if (r0 + i < M) C[(size_t)(r0 + i) * ldc + bn + c] = s;
    }
}

// wave-per-output bias rows: idx<768: Mmat[h*513+512, j] = bapi . T_h[:, j]
// idx in [768,1024): bz[j] = gat_bias . Whead[:, j] + bhead[j]
__global__ __launch_bounds__(256) void brow_kernel(
    const float* __restrict__ bapi, const float* __restrict__ T,
    const float* __restrict__ gat_bias, const float* __restrict__ Whead,
    const float* __restrict__ bhead,
    float* __restrict__ Mmat, float* __restrict__ bz) {
    int wave = threadIdx.x >> 6, lane = threadIdx.x & 63;
    int idx = blockIdx.x * 4 + wave;
    if (idx < H * N_OUT) {
        int h = idx / N_OUT, j = idx % N_OUT;
        float s = 0.f;
#pragma unroll
        for (int i = 0; i < N_INP / 64; ++i) {
            int cc = lane + i * 64;
            s += bapi[cc] * T[((size_t)h * N_INP + cc) * N_OUT + j];
        }
#pragma unroll
        for (int off = 32; off >= 1; off >>= 1) s += __shfl_xor(s, off, 64);
        if (lane == 0) Mmat[((size_t)(h * 513 + 512)) * N_OUT + j] = s;
    } else if (idx < H * N_OUT + N_OUT) {
        int j = idx - H * N_OUT;
        float s = 0.f;
#pragma unroll
        for (int i = 0; i < HD / 64; ++i) {
            int f = lane + i * 64;
            s += gat_bias[f] * Whead[(size_t)f * N_OUT + j];
        }
#pragma unroll
        for (int off = 32; off >= 1; off >>= 1) s += __shfl_xor(s, off, 64);
        if (lane == 0) bz[j] = s + bhead[j];
    }
}

// MmatT_bf16[n, k] (K-contiguous, padded): k = h*HSTR + c -> Mmat[h*513+c, n], else 0
__global__ void convT_kernel(const float* __restrict__ Mmat, unsigned short* __restrict__ MmatT) {
    int idx = blockIdx.x * blockDim.x + threadIdx.x;
    if (idx >= N_OUT * KP) return;
    int n = idx / KP, k = idx % KP;
    float v = 0.f;
    if (k < H * HSTR) {
        int h = k / HSTR, c = k % HSTR;
        if (c < 513) v = Mmat[((size_t)(h * 513 + c)) * N_OUT + n];
    }
    MmatT[(size_t)n * KP + k] = f2bf(v);
}

// bf16 MFMA GEMM: C[M,256] = A[M,KP] @ BT[256,KP]^T + bias
// 128x128 tile, BK=32, 4 waves (2x2 of 64x64, acc[4][4]). 2-phase async
// pipeline per the proven template (learn_hip m230): STAGE(next) at iter start
// via global_load_lds (16B), ds_read frags + MFMA in the middle, single
// vmcnt(0)+s_barrier at iter end (one barrier per k-step; a full iteration of
// latency cover for the staged loads). No atomics. Grid (2, 157) = 314 blocks.
__global__ __launch_bounds__(256) void gemm_mfma(
    const unsigned short* __restrict__ A, const unsigned short* __restrict__ BT,
    const float* __restrict__ bias, float* __restrict__ C, int M) {
    __shared__ __align__(16) short As[2][128 * 32];   // 2 x 8 KB
    __shared__ __align__(16) short Bs[2][128 * 32];   // 2 x 8 KB
    int tid = threadIdx.x;
    int wave = tid >> 6, lane = tid & 63;
    int bm = blockIdx.y * 128, bn = blockIdx.x * 128;
    int wm = (wave >> 1) * 64, wn = (wave & 1) * 64;
    int quad = lane >> 4, m16 = lane & 15;
    // staging geometry: wave w, issue p covers rows p*64 + w*16 + (lane>>2);
    // lane loads 16B at k-chunk (lane&3)*8 -> LDS linear [row][32] layout.
    int srow = lane >> 2;
    int schunk = (lane & 3) * 8;

    f32x4 acc[4][4] = {};

    auto stage = [&](int buf, int k0) {
#pragma unroll
        for (int p = 0; p < 2; ++p) {
            int row = p * 64 + wave * 16 + srow;
            int ar = bm + row; if (ar >= M) ar = M - 1;   // clamp; masked at epilogue
            glds16(A + (size_t)ar * KP + k0 + schunk, &As[buf][(p * 64 + wave * 16) * 32]);
            glds16(BT + (size_t)(bn + row) * KP + k0 + schunk, &Bs[buf][(p * 64 + wave * 16) * 32]);
        }
    };

    stage(0, 0);
    asm volatile("s_waitcnt vmcnt(0)" ::: "memory");
    __builtin_amdgcn_s_barrier();
    asm volatile("" ::: "memory");
    int cur = 0;
    for (int t = 0; t < GEMM_NT; ++t) {
        if (t + 1 < GEMM_NT) stage(cur ^ 1, (t + 1) * 32);   // next tile in flight
        short8 af[4], bf[4];
#pragma unroll
        for (int x = 0; x < 4; ++x) {
            af[x] = *(const short8*)(&As[cur][(wm + x * 16 + m16) * 32 + quad * 8]);
            bf[x] = *(const short8*)(&Bs[cur][(wn + x * 16 + m16) * 32 + quad * 8]);
        }
        asm volatile("s_waitcnt lgkmcnt(0)" ::: "memory");
        __builtin_amdgcn_sched_barrier(0);
#pragma unroll
        for (int mt = 0; mt < 4; ++mt)
#pragma unroll
            for (int nt = 0; nt < 4; ++nt)
                acc[mt][nt] = __builtin_amdgcn_mfma_f32_16x16x32_bf16(
                    af[mt], bf[nt], acc[mt][nt], 0, 0, 0);
        __builtin_amdgcn_sched_barrier(0);
        if (t + 1 < GEMM_NT) asm volatile("s_waitcnt vmcnt(0)" ::: "memory");
        __builtin_amdgcn_s_barrier();
        asm volatile("" ::: "memory");
        cur ^= 1;
    }
#pragma unroll
    for (int mt = 0; mt < 4; ++mt) {
#pragma unroll
        for (int i = 0; i < 4; ++i) {
            int r = bm + wm + mt * 16 + quad * 4 + i;
            if (r >= M) continue;
#pragma unroll
            for (int nt = 0; nt < 4; ++nt) {
                int col = bn + wn + nt * 16 + m16;
                C[(size_t)r * N_OUT + col] = acc[mt][nt][i] + bias[col];
            }
        }
    }
}

// ---------------------------------------------------------------------------
extern "C" void kernel_launch(void* const* d_in, const int* in_sizes, int n_in,
                              void* d_out, int out_size, void* d_ws, size_t ws_size,
                              hipStream_t stream) {
    const float* emb_api  = (const float*)d_in[0];
    const float* emb_file = (const float*)d_in[1];
    // d_in[2] = e_tensor (unused by the reference)
    const int*   src      = (const int*)d_in[3];
    const int*   dst      = (const int*)d_in[4];
    const float* Wapi     = (const float*)d_in[5];
    const float* bapi     = (const float*)d_in[6];
    const float* Wfile    = (const float*)d_in[7];
    const float* bfile    = (const float*)d_in[8];
    const float* Wsrc     = (const float*)d_in[9];
    const float* Wdst     = (const float*)d_in[10];
    const float* attn_l   = (const float*)d_in[11];
    const float* attn_r   = (const float*)d_in[12];
    const float* gat_bias = (const float*)d_in[13];
    const float* Whead    = (const float*)d_in[14];
    const float* bhead    = (const float*)d_in[15];
    float* out = (float*)d_out;

    const int NAPI = in_sizes[0] / N_INP;   // 50000
    const int NFIL = in_sizes[1] / N_INP;   // 20000
    const int E    = in_sizes[3];           // 250000

    // workspace carve-up
    char* p = (char*)d_ws;
    auto alloc = [&](size_t bytes) -> void* {
        void* r = (void*)p;
        p += (bytes + 255) & ~(size_t)255;
        return r;
    };
    float* el      = (float*)alloc((size_t)NAPI * H * 4);
    float* er      = (float*)alloc((size_t)NFIL * H * 4);
    float* vbuf    = (float*)alloc(2 * H * N_INP * 4);
    float* ubuf    = (float*)alloc(2 * H * N_INP * 4);
    float* ebias   = (float*)alloc(8 * 4);
    float* T       = (float*)alloc((size_t)H * N_INP * N_OUT * 4);
    float* Mmat    = (float*)alloc((size_t)AGG_D * N_OUT * 4);
    float* bz      = (float*)alloc(N_OUT * 4);
    int*   counts  = (int*)alloc((size_t)NFIL * 4);
    int*   offsets = (int*)alloc((size_t)(NFIL + 1) * 4);
    int*   cursor  = (int*)alloc((size_t)NFIL * 4);
    int*   csr_src = (int*)alloc((size_t)E * 4);
    unsigned short* embB  = (unsigned short*)alloc((size_t)NAPI * N_INP * 2);
    unsigned short* aggB  = (unsigned short*)alloc((size_t)NFIL * KP * 2);
    unsigned short* MmatT = (unsigned short*)alloc((size_t)N_OUT * KP * 2);
    (void)ws_size; (void)n_in; (void)out_size;

    // --- weight precompute (tiny, parallelism-first) ---
    v_kernel<<<(2 * H * N_INP + 3) / 4, 256, 0, stream>>>(Wsrc, Wdst, attn_l, attn_r, vbuf);
    u_kernel<<<(2 * H * N_INP + 6 + 3) / 4, 256, 0, stream>>>(Wapi, Wfile, bapi, bfile, vbuf, ubuf, ebias);
    // T_h = Wsrc[:, h*256:(h+1)*256] @ Whead[h*256:(h+1)*256, :]  (batched over h)
    wgemm<N_OUT><<<dim3(N_INP / 8, 4, H), 256, 0, stream>>>(
        Wsrc, HD, (size_t)N_OUT,
        Whead, N_OUT, (size_t)N_OUT * N_OUT,
        T, N_OUT, (size_t)N_INP * N_OUT, N_INP);
    // Mmat rows [h*513 .. h*513+511] = Wapi @ T_h  (batched over h)
    wgemm<N_INP><<<dim3(N_INP / 8, 4, H), 256, 0, stream>>>(
        Wapi, N_INP, (size_t)0,
        T, N_OUT, (size_t)N_INP * N_OUT,
        Mmat, N_OUT, (size_t)513 * N_OUT, N_INP);
    brow_kernel<<<(H * N_OUT + N_OUT + 3) / 4, 256, 0, stream>>>(
        bapi, T, gat_bias, Whead, bhead, Mmat, bz);
    convT_kernel<<<(N_OUT * KP + 255) / 256, 256, 0, stream>>>(Mmat, MmatT);

    // --- attention logits for both sides (+ bf16 emb copy + counts zeroing) ---
    elr2_kernel<<<(NAPI + NFIL + 3) / 4, 256, 0, stream>>>(
        emb_api, emb_file, ubuf, ebias, el, er, embB, counts, NAPI, NFIL);

    // --- CSR build (by dst) ---
    count_kernel<<<(E + 255) / 256, 256, 0, stream>>>(dst, counts, E);
    scan_kernel<<<1, 1024, 0, stream>>>(counts, offsets, cursor, NFIL);
    scatter_kernel<<<(E + 255) / 256, 256, 0, stream>>>(src, dst, cursor, csr_src, E);

    // --- fused edge softmax + aggregation (bf16 out) ---
    agg_kernel<<<NFIL, 256, 0, stream>>>(offsets, csr_src, el, er, embB, aggB, NFIL);

    // --- final fused GEMM (bf16 MFMA): out = aggB @ MmatT^T + bz ---
    gemm_mfma<<<dim3(2, (NFIL + 127) / 128), 256, 0, stream>>>(
        aggB, MmatT, bz, out, NFIL);
}

// Round 7
// 444.939 us; speedup vs baseline: 1.0246x; 1.0246x over previous
//
#include <hip/hip_runtime.h>
#include <hip/hip_bf16.h>
#include <cstdint>
#include <cstddef>

// Dims (fixed by the problem)
#define N_INP 512
#define N_OUT 256
#define H 3
#define HD (H * N_OUT)       // 768
#define AGG_D (H * (N_INP + 1))  // 1539 logical (513 per head: 512 emb + 1 homogeneous)
#define HSTR 522             // per-head stride in bf16 agg (keeps 4B alignment, room for pad)
#define KP 1568              // padded K for MFMA GEMM (multiple of 32; 3*522=1566 <= 1568)
#define GEMM_NT (KP / 32)    // 49 k-steps

typedef __attribute__((ext_vector_type(8))) short short8;
typedef __attribute__((ext_vector_type(4))) float f32x4;

__device__ inline unsigned short f2bf(float x) {
    union { float f; unsigned u; } v; v.f = x;
    unsigned r = v.u + 0x7fffu + ((v.u >> 16) & 1u);  // RNE
    return (unsigned short)(r >> 16);
}
__device__ inline float bflo2f(unsigned u) {  // low 16 bits -> float
    union { unsigned u; float f; } v; v.u = u << 16; return v.f;
}
__device__ inline float bfhi2f(unsigned u) {  // high 16 bits -> float
    union { unsigned u; float f; } v; v.u = u & 0xffff0000u; return v.f;
}

// async global->LDS, 16B per lane. LDS dest is the wave-uniform base;
// HW writes lane i at base + i*16.
__device__ inline void glds16(const void* g, void* l) {
    __builtin_amdgcn_global_load_lds(
        (const __attribute__((address_space(1))) void*)g,
        (__attribute__((address_space(3))) void*)l, 16, 0, 0);
}

// ---------------------------------------------------------------------------
// small utility kernels
// ---------------------------------------------------------------------------

// wave-per-output: v_l[h][o] = sum_t Wsrc[o, h*256+t] * attn_l[h,t]  (v_r: Wdst/attn_r)
__global__ __launch_bounds__(256) void v_kernel(
    const float* __restrict__ Wsrc, const float* __restrict__ Wdst,
    const float* __restrict__ attn_l, const float* __restrict__ attn_r,
    float* __restrict__ v) {
    int wave = threadIdx.x >> 6, lane = threadIdx.x & 63;
    int idx = blockIdx.x * 4 + wave;
    if (idx >= 2 * H * N_INP) return;
    int which = idx / (H * N_INP);
    int r = idx % (H * N_INP);
    int h = r / N_INP, o = r % N_INP;
    const float* W = which ? Wdst : Wsrc;
    const float* at = which ? attn_r : attn_l;
    float s = 0.f;
#pragma unroll
    for (int i = 0; i < N_OUT / 64; ++i) {
        int t = lane + i * 64;
        s += W[(size_t)o * HD + h * N_OUT + t] * at[h * N_OUT + t];
    }
#pragma unroll
    for (int off = 32; off >= 1; off >>= 1) s += __shfl_xor(s, off, 64);
    if (lane == 0) v[idx] = s;
}

// wave-per-output: u (idx<3072) and ebias (idx in [3072,3078))
__global__ __launch_bounds__(256) void u_kernel(
    const float* __restrict__ Wapi, const float* __restrict__ Wfile,
    const float* __restrict__ bapi, const float* __restrict__ bfile,
    const float* __restrict__ v, float* __restrict__ u,
    float* __restrict__ ebias) {
    int wave = threadIdx.x >> 6, lane = threadIdx.x & 63;
    int idx = blockIdx.x * 4 + wave;
    if (idx < 2 * H * N_INP) {
        int which = idx / (H * N_INP);
        int r = idx % (H * N_INP);
        int h = r / N_INP, i = r % N_INP;
        const float* W = which ? Wfile : Wapi;
        const float* vv = v + which * (H * N_INP) + h * N_INP;
        float s = 0.f;
#pragma unroll
        for (int j = 0; j < N_INP / 64; ++j) {
            int o = lane + j * 64;
            s += W[(size_t)i * N_INP + o] * vv[o];
        }
#pragma unroll
        for (int off = 32; off >= 1; off >>= 1) s += __shfl_xor(s, off, 64);
        if (lane == 0) u[idx] = s;
    } else if (idx < 2 * H * N_INP + 6) {
        int k = idx - 2 * H * N_INP;
        int which = k / H, h = k % H;
        const float* b = which ? bfile : bapi;
        const float* vv = v + which * (H * N_INP) + h * N_INP;
        float s = 0.f;
#pragma unroll
        for (int j = 0; j < N_INP / 64; ++j) {
            int o = lane + j * 64;
            s += b[o] * vv[o];
        }
#pragma unroll
        for (int off = 32; off >= 1; off >>= 1) s += __shfl_xor(s, off, 64);
        if (lane == 0) ebias[k] = s;
    }
}

// el[n,h] = emb[n,:] . u[h,:] + ebias[h]   (one wave per node)
// optionally writes a bf16 copy of emb rows; optionally zeroes counts[0..nz)
__global__ __launch_bounds__(256) void elr_kernel(
    const float* __restrict__ emb, const float* __restrict__ u,
    const float* __restrict__ ebias, float* __restrict__ out,
    unsigned short* __restrict__ embB, int* __restrict__ zero_p, int nz, int n) {
    __shared__ float su[H * N_INP];
    if (zero_p) {
        int zi = blockIdx.x * 256 + threadIdx.x;
        if (zi < nz) zero_p[zi] = 0;
    }
    for (int i = threadIdx.x; i < H * N_INP; i += 256) su[i] = u[i];
    __syncthreads();
    int wave = threadIdx.x >> 6;
    int lane = threadIdx.x & 63;
    int node = blockIdx.x * 4 + wave;
    if (node >= n) return;
    const float4* row = (const float4*)(emb + (size_t)node * N_INP);
    float4 v0 = row[lane];        // cols lane*4 .. +3
    float4 v1 = row[64 + lane];   // cols 256+lane*4 .. +3
    int c0 = lane * 4, c1 = 256 + lane * 4;
    if (embB) {
        unsigned short* o = embB + (size_t)node * N_INP;
        ushort4 p0, p1;
        p0.x = f2bf(v0.x); p0.y = f2bf(v0.y); p0.z = f2bf(v0.z); p0.w = f2bf(v0.w);
        p1.x = f2bf(v1.x); p1.y = f2bf(v1.y); p1.z = f2bf(v1.z); p1.w = f2bf(v1.w);
        *(ushort4*)(o + c0) = p0;
        *(ushort4*)(o + c1) = p1;
    }
    float d[H];
#pragma unroll
    for (int h = 0; h < H; ++h) {
        const float* uh = su + h * N_INP;
        d[h] = v0.x * uh[c0] + v0.y * uh[c0 + 1] + v0.z * uh[c0 + 2] + v0.w * uh[c0 + 3]
             + v1.x * uh[c1] + v1.y * uh[c1 + 1] + v1.z * uh[c1 + 2] + v1.w * uh[c1 + 3];
#pragma unroll
        for (int off = 32; off >= 1; off >>= 1) d[h] += __shfl_xor(d[h], off, 64);
    }
    if (lane == 0) {
#pragma unroll
        for (int h = 0; h < H; ++h) out[(size_t)node * H + h] = d[h] + ebias[h];
    }
}

__global__ void count_kernel(const int* __restrict__ dst, int* __restrict__ counts, int E) {
    int e = blockIdx.x * blockDim.x + threadIdx.x;
    if (e < E) atomicAdd(&counts[dst[e]], 1);
}

// single-block exclusive scan of counts -> offsets, cursor; offsets[n] = total
__global__ __launch_bounds__(1024) void scan_kernel(const int* __restrict__ counts,
                                                    int* __restrict__ offsets,
                                                    int* __restrict__ cursor, int n) {
    __shared__ int part[1024];
    int t = threadIdx.x;
    const int CH = (n + 1023) / 1024;
    int lo = t * CH, hi = min(lo + CH, n);
    int s = 0;
    for (int i = lo; i < hi; ++i) s += counts[i];
    part[t] = s;
    __syncthreads();
    for (int off = 1; off < 1024; off <<= 1) {
        int v = (t >= off) ? part[t - off] : 0;
        __syncthreads();
        part[t] += v;
        __syncthreads();
    }
    int base = (t == 0) ? 0 : part[t - 1];
    for (int i = lo; i < hi; ++i) {
        offsets[i] = base; cursor[i] = base;
        base += counts[i];
    }
    if (t == 1023) offsets[n] = part[1023];
}

__global__ void scatter_kernel(const int* __restrict__ src, const int* __restrict__ dst,
                               int* __restrict__ cursor, int* __restrict__ csr_src, int E) {
    int e = blockIdx.x * blockDim.x + threadIdx.x;
    if (e < E) {
        int slot = atomicAdd(&cursor[dst[e]], 1);
        csr_src[slot] = src[e];
    }
}

// one block (256 threads) per dst node: FUSED edge-softmax + aggregation,
// SINGLE el-gather. Fast path (deg <= 512, i.e. ~always at E/nd = 12.5):
// stage {src_idx, leaky(el+er)} per edge into LDS once; max / exp-in-place /
// sum / scale are cheap LDS passes; then the x4-unrolled embB gather.
// Slow path (deg > 512): 3-phase re-gather (correctness fallback).
// aggB[d, h*HSTR + 512] = (deg>0) ? 1 : 0 ; cols [513,HSTR) and [3*HSTR,KP) pad 0.
#define AGG_CH 512
__global__ __launch_bounds__(256) void agg_kernel(
    const int* __restrict__ offsets, const int* __restrict__ csr_src,
    const float* __restrict__ el, const float* __restrict__ er,
    const unsigned short* __restrict__ embB,
    unsigned short* __restrict__ aggB, int nd) {
    __shared__ int su[AGG_CH];
    __shared__ float sw0[AGG_CH], sw1[AGG_CH], sw2[AGG_CH];
    __shared__ float sred[12], sm[3], sz[3];
    int d = blockIdx.x;
    if (d >= nd) return;
    int tid = threadIdx.x, wave = tid >> 6, lane = tid & 63;
    int lo = offsets[d], hi = offsets[d + 1], cnt = hi - lo;
    float er0 = er[(size_t)d * H + 0], er1 = er[(size_t)d * H + 1], er2 = er[(size_t)d * H + 2];
    const unsigned* ebdw = (const unsigned*)embB;   // 256 dwords per row
    float a00 = 0.f, a01 = 0.f, a10 = 0.f, a11 = 0.f, a20 = 0.f, a21 = 0.f;

    if (cnt <= AGG_CH) {
        // ---- fast path: one gather, softmax over LDS ----
        for (int i = tid; i < cnt; i += 256) {
            int uu = csr_src[lo + i];
            su[i] = uu;
            float e0 = el[(size_t)uu * H + 0] + er0; e0 = e0 >= 0.f ? e0 : 0.2f * e0;
            float e1 = el[(size_t)uu * H + 1] + er1; e1 = e1 >= 0.f ? e1 : 0.2f * e1;
            float e2 = el[(size_t)uu * H + 2] + er2; e2 = e2 >= 0.f ? e2 : 0.2f * e2;
            sw0[i] = e0; sw1[i] = e1; sw2[i] = e2;
        }
        __syncthreads();
        // max
        float p0 = -3.4e38f, p1 = -3.4e38f, p2 = -3.4e38f;
        for (int i = tid; i < cnt; i += 256) {
            p0 = fmaxf(p0, sw0[i]); p1 = fmaxf(p1, sw1[i]); p2 = fmaxf(p2, sw2[i]);
        }
#pragma unroll
        for (int off = 32; off >= 1; off >>= 1) {
            p0 = fmaxf(p0, __shfl_xor(p0, off, 64));
            p1 = fmaxf(p1, __shfl_xor(p1, off, 64));
            p2 = fmaxf(p2, __shfl_xor(p2, off, 64));
        }
        if (lane == 0) { sred[wave * 3 + 0] = p0; sred[wave * 3 + 1] = p1; sred[wave * 3 + 2] = p2; }
        __syncthreads();
        if (tid < 3) {
            float v = sred[tid];
            v = fmaxf(v, sred[3 + tid]); v = fmaxf(v, sred[6 + tid]); v = fmaxf(v, sred[9 + tid]);
            sm[tid] = v;
        }
        __syncthreads();
        float m0 = sm[0], m1 = sm[1], m2 = sm[2];
        // exp in place + sum
        p0 = 0.f; p1 = 0.f; p2 = 0.f;
        for (int i = tid; i < cnt; i += 256) {
            float w0 = expf(sw0[i] - m0), w1 = expf(sw1[i] - m1), w2 = expf(sw2[i] - m2);
            sw0[i] = w0; sw1[i] = w1; sw2[i] = w2;
            p0 += w0; p1 += w1; p2 += w2;
        }
#pragma unroll
        for (int off = 32; off >= 1; off >>= 1) {
            p0 += __shfl_xor(p0, off, 64);
            p1 += __shfl_xor(p1, off, 64);
            p2 += __shfl_xor(p2, off, 64);
        }
        if (lane == 0) { sred[wave * 3 + 0] = p0; sred[wave * 3 + 1] = p1; sred[wave * 3 + 2] = p2; }
        __syncthreads();
        if (tid < 3) sz[tid] = sred[tid] + sred[3 + tid] + sred[6 + tid] + sred[9 + tid];
        __syncthreads();
        float iz0 = 1.f / sz[0], iz1 = 1.f / sz[1], iz2 = 1.f / sz[2];
        for (int i = tid; i < cnt; i += 256) {
            sw0[i] *= iz0; sw1[i] *= iz1; sw2[i] *= iz2;
        }
        __syncthreads();
        // gather embB, unrolled x4
        int i = 0;
        for (; i + 4 <= cnt; i += 4) {
            int u0 = su[i], u1 = su[i + 1], u2 = su[i + 2], u3 = su[i + 3];
            unsigned v0 = ebdw[((size_t)u0 << 8) + tid];
            unsigned v1 = ebdw[((size_t)u1 << 8) + tid];
            unsigned v2 = ebdw[((size_t)u2 << 8) + tid];
            unsigned v3 = ebdw[((size_t)u3 << 8) + tid];
            float w00 = sw0[i], w01 = sw1[i], w02 = sw2[i];
            float w10 = sw0[i+1], w11 = sw1[i+1], w12 = sw2[i+1];
            float w20 = sw0[i+2], w21 = sw1[i+2], w22 = sw2[i+2];
            float w30 = sw0[i+3], w31 = sw1[i+3], w32 = sw2[i+3];
            float x, y;
            x = bflo2f(v0); y = bfhi2f(v0);
            a00 += w00 * x; a01 += w00 * y; a10 += w01 * x; a11 += w01 * y; a20 += w02 * x; a21 += w02 * y;
            x = bflo2f(v1); y = bfhi2f(v1);
            a00 += w10 * x; a01 += w10 * y; a10 += w11 * x; a11 += w11 * y; a20 += w12 * x; a21 += w12 * y;
            x = bflo2f(v2); y = bfhi2f(v2);
            a00 += w20 * x; a01 += w20 * y; a10 += w21 * x; a11 += w21 * y; a20 += w22 * x; a21 += w22 * y;
            x = bflo2f(v3); y = bfhi2f(v3);
            a00 += w30 * x; a01 += w30 * y; a10 += w31 * x; a11 += w31 * y; a20 += w32 * x; a21 += w32 * y;
        }
        for (; i < cnt; ++i) {
            int uu = su[i];
            unsigned v = ebdw[((size_t)uu << 8) + tid];
            float w0 = sw0[i], w1 = sw1[i], w2 = sw2[i];
            float x = bflo2f(v), y = bfhi2f(v);
            a00 += w0 * x; a01 += w0 * y;
            a10 += w1 * x; a11 += w1 * y;
            a20 += w2 * x; a21 += w2 * y;
        }
    } else {
        // ---- slow path (deg > 512): 3-phase with re-gather ----
        float p0 = -3.4e38f, p1 = -3.4e38f, p2 = -3.4e38f;
        for (int i = tid; i < cnt; i += 256) {
            int uu = csr_src[lo + i];
            float e0 = el[(size_t)uu * H + 0] + er0; e0 = e0 >= 0.f ? e0 : 0.2f * e0;
            float e1 = el[(size_t)uu * H + 1] + er1; e1 = e1 >= 0.f ? e1 : 0.2f * e1;
            float e2 = el[(size_t)uu * H + 2] + er2; e2 = e2 >= 0.f ? e2 : 0.2f * e2;
            p0 = fmaxf(p0, e0); p1 = fmaxf(p1, e1); p2 = fmaxf(p2, e2);
        }
#pragma unroll
        for (int off = 32; off >= 1; off >>= 1) {
            p0 = fmaxf(p0, __shfl_xor(p0, off, 64));
            p1 = fmaxf(p1, __shfl_xor(p1, off, 64));
            p2 = fmaxf(p2, __shfl_xor(p2, off, 64));
        }
        if (lane == 0) { sred[wave * 3 + 0] = p0; sred[wave * 3 + 1] = p1; sred[wave * 3 + 2] = p2; }
        __syncthreads();
        if (tid < 3) {
            float v = sred[tid];
            v = fmaxf(v, sred[3 + tid]); v = fmaxf(v, sred[6 + tid]); v = fmaxf(v, sred[9 + tid]);
            sm[tid] = v;
        }
        __syncthreads();
        float m0 = sm[0], m1 = sm[1], m2 = sm[2];
        p0 = 0.f; p1 = 0.f; p2 = 0.f;
        for (int i = tid; i < cnt; i += 256) {
            int uu = csr_src[lo + i];
            float e0 = el[(size_t)uu * H + 0] + er0; e0 = e0 >= 0.f ? e0 : 0.2f * e0;
            float e1 = el[(size_t)uu * H + 1] + er1; e1 = e1 >= 0.f ? e1 : 0.2f * e1;
            float e2 = el[(size_t)uu * H + 2] + er2; e2 = e2 >= 0.f ? e2 : 0.2f * e2;
            p0 += expf(e0 - m0); p1 += expf(e1 - m1); p2 += expf(e2 - m2);
        }
#pragma unroll
        for (int off = 32; off >= 1; off >>= 1) {
            p0 += __shfl_xor(p0, off, 64);
            p1 += __shfl_xor(p1, off, 64);
            p2 += __shfl_xor(p2, off, 64);
        }
        if (lane == 0) { sred[wave * 3 + 0] = p0; sred[wave * 3 + 1] = p1; sred[wave * 3 + 2] = p2; }
        __syncthreads();
        if (tid < 3) sz[tid] = sred[tid] + sred[3 + tid] + sred[6 + tid] + sred[9 + tid];
        __syncthreads();
        float iz0 = 1.f / sz[0], iz1 = 1.f / sz[1], iz2 = 1.f / sz[2];
        for (int baseE = lo; baseE < hi; baseE += AGG_CH) {
            int cc = min(hi - baseE, AGG_CH);
            for (int i = tid; i < cc; i += 256) {
                int uu = csr_src[baseE + i];
                su[i] = uu;
                float e0 = el[(size_t)uu * H + 0] + er0; e0 = e0 >= 0.f ? e0 : 0.2f * e0;
                float e1 = el[(size_t)uu * H + 1] + er1; e1 = e1 >= 0.f ? e1 : 0.2f * e1;
                float e2 = el[(size_t)uu * H + 2] + er2; e2 = e2 >= 0.f ? e2 : 0.2f * e2;
                sw0[i] = expf(e0 - m0) * iz0;
                sw1[i] = expf(e1 - m1) * iz1;
                sw2[i] = expf(e2 - m2) * iz2;
            }
            __syncthreads();
            for (int i = 0; i < cc; ++i) {
                int uu = su[i];
                unsigned v = ebdw[((size_t)uu << 8) + tid];
                float w0 = sw0[i], w1 = sw1[i], w2 = sw2[i];
                float x = bflo2f(v), y = bfhi2f(v);
                a00 += w0 * x; a01 += w0 * y;
                a10 += w1 * x; a11 += w1 * y;
                a20 += w2 * x; a21 += w2 * y;
            }
            __syncthreads();
        }
    }
    int c = tid * 2;
    size_t base = (size_t)d * KP;
    *(unsigned*)(aggB + base + 0 * HSTR + c) = (unsigned)f2bf(a00) | ((unsigned)f2bf(a01) << 16);
    *(unsigned*)(aggB + base + 1 * HSTR + c) = (unsigned)f2bf(a10) | ((unsigned)f2bf(a11) << 16);
    *(unsigned*)(aggB + base + 2 * HSTR + c) = (unsigned)f2bf(a20) | ((unsigned)f2bf(a21) << 16);
    if (tid == 0) {
        unsigned short flag = (cnt > 0) ? (unsigned short)0x3f80 : (unsigned short)0; // bf16 1.0 / 0.0
#pragma unroll
        for (int h = 0; h < H; ++h) {
            aggB[base + h * HSTR + 512] = flag;
            for (int z = 513; z < HSTR; ++z) aggB[base + h * HSTR + z] = 0;
        }
        aggB[base + 3 * HSTR + 0] = 0;
        aggB[base + 3 * HSTR + 1] = 0;
    }
}

// weight GEMM with MLP + TLP: C[M,256] = A[M,K] @ B[K,256], batched over blockIdx.z.
template <int K>
__global__ __launch_bounds__(256) void wgemm(
    const float* __restrict__ A, int lda, size_t sAz,
    const float* __restrict__ B, int ldb, size_t sBz,
    float* __restrict__ C, int ldc, size_t sCz, int M) {
    A += blockIdx.z * sAz; B += blockIdx.z * sBz; C += blockIdx.z * sCz;
    __shared__ float sA[8 * K];
    __shared__ float red[8 * 256];   // 8 rows x (4 ksub x 64 cols)
    int tid = threadIdx.x;
    int r0 = blockIdx.x * 8;
    int bn = blockIdx.y * 64;
    for (int i = tid; i < 8 * K; i += 256) {
        int r = i / K, k = i % K;
        sA[i] = A[(size_t)(r0 + r) * lda + k];
    }
    __syncthreads();
    int cl = tid & 63, ks = tid >> 6;
    int col = bn + cl;
    const int KC = K / 4;
    float acc[8] = {};
    for (int k0 = ks * KC; k0 < ks * KC + KC; k0 += 8) {
        float b[8];
#pragma unroll
        for (int j = 0; j < 8; ++j) b[j] = B[(size_t)(k0 + j) * ldb + col];
#pragma unroll
        for (int j = 0; j < 8; ++j) {
            float bb = b[j];
#pragma unroll
            for (int i = 0; i < 8; ++i) acc[i] += sA[i * K + k0 + j] * bb;
        }
    }
#pragma unroll
    for (int i = 0; i < 8; ++i) red[i * 256 + ks * 64 + cl] = acc[i];
    __syncthreads();
    for (int t = tid; t < 512; t += 256) {
        int i = t >> 6, c = t & 63;
        float s = red[i * 256 + c] + red[i * 256 + 64 + c]
                + red[i * 256 + 128 + c] + red[i * 256 + 192 + c];
        if (r0 + i < M) C[(size_t)(r0 + i) * ldc + bn + c] = s;
    }
}

// wave-per-output bias rows: idx<768: Mmat[h*513+512, j] = bapi . T_h[:, j]
// idx in [768,1024): bz[j] = gat_bias . Whead[:, j] + bhead[j]
__global__ __launch_bounds__(256) void brow_kernel(
    const float* __restrict__ bapi, const float* __restrict__ T,
    const float* __restrict__ gat_bias, const float* __restrict__ Whead,
    const float* __restrict__ bhead,
    float* __restrict__ Mmat, float* __restrict__ bz) {
    int wave = threadIdx.x >> 6, lane = threadIdx.x & 63;
    int idx = blockIdx.x * 4 + wave;
    if (idx < H * N_OUT) {
        int h = idx / N_OUT, j = idx % N_OUT;
        float s = 0.f;
#pragma unroll
        for (int i = 0; i < N_INP / 64; ++i) {
            int cc = lane + i * 64;
            s += bapi[cc] * T[((size_t)h * N_INP + cc) * N_OUT + j];
        }
#pragma unroll
        for (int off = 32; off >= 1; off >>= 1) s += __shfl_xor(s, off, 64);
        if (lane == 0) Mmat[((size_t)(h * 513 + 512)) * N_OUT + j] = s;
    } else if (idx < H * N_OUT + N_OUT) {
        int j = idx - H * N_OUT;
        float s = 0.f;
#pragma unroll
        for (int i = 0; i < HD / 64; ++i) {
            int f = lane + i * 64;
            s += gat_bias[f] * Whead[(size_t)f * N_OUT + j];
        }
#pragma unroll
        for (int off = 32; off >= 1; off >>= 1) s += __shfl_xor(s, off, 64);
        if (lane == 0) bz[j] = s + bhead[j];
    }
}

// MmatT_bf16[n, k] (K-contiguous, padded): k = h*HSTR + c -> Mmat[h*513+c, n], else 0
__global__ void convT_kernel(const float* __restrict__ Mmat, unsigned short* __restrict__ MmatT) {
    int idx = blockIdx.x * blockDim.x + threadIdx.x;
    if (idx >= N_OUT * KP) return;
    int n = idx / KP, k = idx % KP;
    float v = 0.f;
    if (k < H * HSTR) {
        int h = k / HSTR, c = k % HSTR;
        if (c < 513) v = Mmat[((size_t)(h * 513 + c)) * N_OUT + n];
    }
    MmatT[(size_t)n * KP + k] = f2bf(v);
}

// bf16 MFMA GEMM: C[M,256] = A[M,KP] @ BT[256,KP]^T + bias
// 128x128 tile, BK=32, 4 waves (2x2 of 64x64, acc[4][4]). 2-phase async
// pipeline (learn_hip m230 template): STAGE(next) at iter start via
// global_load_lds (16B), ds_read frags + MFMA in the middle, single
// vmcnt(0)+s_barrier at iter end. No atomics. Grid (2, 157) = 314 blocks.
__global__ __launch_bounds__(256) void gemm_mfma(
    const unsigned short* __restrict__ A, const unsigned short* __restrict__ BT,
    const float* __restrict__ bias, float* __restrict__ C, int M) {
    __shared__ __align__(16) short As[2][128 * 32];   // 2 x 8 KB
    __shared__ __align__(16) short Bs[2][128 * 32];   // 2 x 8 KB
    int tid = threadIdx.x;
    int wave = tid >> 6, lane = tid & 63;
    int bm = blockIdx.y * 128, bn = blockIdx.x * 128;
    int wm = (wave >> 1) * 64, wn = (wave & 1) * 64;
    int quad = lane >> 4, m16 = lane & 15;
    int srow = lane >> 2;
    int schunk = (lane & 3) * 8;

    f32x4 acc[4][4] = {};

    auto stage = [&](int buf, int k0) {
#pragma unroll
        for (int p = 0; p < 2; ++p) {
            int row = p * 64 + wave * 16 + srow;
            int ar = bm + row; if (ar >= M) ar = M - 1;   // clamp; masked at epilogue
            glds16(A + (size_t)ar * KP + k0 + schunk, &As[buf][(p * 64 + wave * 16) * 32]);
            glds16(BT + (size_t)(bn + row) * KP + k0 + schunk, &Bs[buf][(p * 64 + wave * 16) * 32]);
        }
    };

    stage(0, 0);
    asm volatile("s_waitcnt vmcnt(0)" ::: "memory");
    __builtin_amdgcn_s_barrier();
    asm volatile("" ::: "memory");
    int cur = 0;
    for (int t = 0; t < GEMM_NT; ++t) {
        if (t + 1 < GEMM_NT) stage(cur ^ 1, (t + 1) * 32);   // next tile in flight
        short8 af[4], bf[4];
#pragma unroll
        for (int x = 0; x < 4; ++x) {
            af[x] = *(const short8*)(&As[cur][(wm + x * 16 + m16) * 32 + quad * 8]);
            bf[x] = *(const short8*)(&Bs[cur][(wn + x * 16 + m16) * 32 + quad * 8]);
        }
        asm volatile("s_waitcnt lgkmcnt(0)" ::: "memory");
        __builtin_amdgcn_sched_barrier(0);
#pragma unroll
        for (int mt = 0; mt < 4; ++mt)
#pragma unroll
            for (int nt = 0; nt < 4; ++nt)
                acc[mt][nt] = __builtin_amdgcn_mfma_f32_16x16x32_bf16(
                    af[mt], bf[nt], acc[mt][nt], 0, 0, 0);
        __builtin_amdgcn_sched_barrier(0);
        if (t + 1 < GEMM_NT) asm volatile("s_waitcnt vmcnt(0)" ::: "memory");
        __builtin_amdgcn_s_barrier();
        asm volatile("" ::: "memory");
        cur ^= 1;
    }
#pragma unroll
    for (int mt = 0; mt < 4; ++mt) {
#pragma unroll
        for (int i = 0; i < 4; ++i) {
            int r = bm + wm + mt * 16 + quad * 4 + i;
            if (r >= M) continue;
#pragma unroll
            for (int nt = 0; nt < 4; ++nt) {
                int col = bn + wn + nt * 16 + m16;
                C[(size_t)r * N_OUT + col] = acc[mt][nt][i] + bias[col];
            }
        }
    }
}

// ---------------------------------------------------------------------------
extern "C" void kernel_launch(void* const* d_in, const int* in_sizes, int n_in,
                              void* d_out, int out_size, void* d_ws, size_t ws_size,
                              hipStream_t stream) {
    const float* emb_api  = (const float*)d_in[0];
    const float* emb_file = (const float*)d_in[1];
    // d_in[2] = e_tensor (unused by the reference)
    const int*   src      = (const int*)d_in[3];
    const int*   dst      = (const int*)d_in[4];
    const float* Wapi     = (const float*)d_in[5];
    const float* bapi     = (const float*)d_in[6];
    const float* Wfile    = (const float*)d_in[7];
    const float* bfile    = (const float*)d_in[8];
    const float* Wsrc     = (const float*)d_in[9];
    const float* Wdst     = (const float*)d_in[10];
    const float* attn_l   = (const float*)d_in[11];
    const float* attn_r   = (const float*)d_in[12];
    const float* gat_bias = (const float*)d_in[13];
    const float* Whead    = (const float*)d_in[14];
    const float* bhead    = (const float*)d_in[15];
    float* out = (float*)d_out;

    const int NAPI = in_sizes[0] / N_INP;   // 50000
    const int NFIL = in_sizes[1] / N_INP;   // 20000
    const int E    = in_sizes[3];           // 250000

    // workspace carve-up
    char* p = (char*)d_ws;
    auto alloc = [&](size_t bytes) -> void* {
        void* r = (void*)p;
        p += (bytes + 255) & ~(size_t)255;
        return r;
    };
    float* el      = (float*)alloc((size_t)NAPI * H * 4);
    float* er      = (float*)alloc((size_t)NFIL * H * 4);
    float* vbuf    = (float*)alloc(2 * H * N_INP * 4);
    float* ubuf    = (float*)alloc(2 * H * N_INP * 4);
    float* ebias   = (float*)alloc(8 * 4);
    float* T       = (float*)alloc((size_t)H * N_INP * N_OUT * 4);
    float* Mmat    = (float*)alloc((size_t)AGG_D * N_OUT * 4);
    float* bz      = (float*)alloc(N_OUT * 4);
    int*   counts  = (int*)alloc((size_t)NFIL * 4);
    int*   offsets = (int*)alloc((size_t)(NFIL + 1) * 4);
    int*   cursor  = (int*)alloc((size_t)NFIL * 4);
    int*   csr_src = (int*)alloc((size_t)E * 4);
    unsigned short* embB  = (unsigned short*)alloc((size_t)NAPI * N_INP * 2);
    unsigned short* aggB  = (unsigned short*)alloc((size_t)NFIL * KP * 2);
    unsigned short* MmatT = (unsigned short*)alloc((size_t)N_OUT * KP * 2);
    (void)ws_size; (void)n_in; (void)out_size;

    // --- weight precompute (tiny, parallelism-first) ---
    v_kernel<<<(2 * H * N_INP + 3) / 4, 256, 0, stream>>>(Wsrc, Wdst, attn_l, attn_r, vbuf);
    u_kernel<<<(2 * H * N_INP + 6 + 3) / 4, 256, 0, stream>>>(Wapi, Wfile, bapi, bfile, vbuf, ubuf, ebias);
    // T_h = Wsrc[:, h*256:(h+1)*256] @ Whead[h*256:(h+1)*256, :]  (batched over h)
    wgemm<N_OUT><<<dim3(N_INP / 8, 4, H), 256, 0, stream>>>(
        Wsrc, HD, (size_t)N_OUT,
        Whead, N_OUT, (size_t)N_OUT * N_OUT,
        T, N_OUT, (size_t)N_INP * N_OUT, N_INP);
    // Mmat rows [h*513 .. h*513+511] = Wapi @ T_h  (batched over h)
    wgemm<N_INP><<<dim3(N_INP / 8, 4, H), 256, 0, stream>>>(
        Wapi, N_INP, (size_t)0,
        T, N_OUT, (size_t)N_INP * N_OUT,
        Mmat, N_OUT, (size_t)513 * N_OUT, N_INP);
    brow_kernel<<<(H * N_OUT + N_OUT + 3) / 4, 256, 0, stream>>>(
        bapi, T, gat_bias, Whead, bhead, Mmat, bz);
    convT_kernel<<<(N_OUT * KP + 255) / 256, 256, 0, stream>>>(Mmat, MmatT);

    // --- attention logits (api side also writes bf16 emb copy; file side zeroes counts) ---
    elr_kernel<<<(NAPI + 3) / 4, 256, 0, stream>>>(
        emb_api, ubuf, ebias, el, embB, nullptr, 0, NAPI);
    elr_kernel<<<(NFIL + 3) / 4, 256, 0, stream>>>(
        emb_file, ubuf + H * N_INP, ebias + 3, er, nullptr, counts, NFIL, NFIL);

    // --- CSR build (by dst) ---
    count_kernel<<<(E + 255) / 256, 256, 0, stream>>>(dst, counts, E);
    scan_kernel<<<1, 1024, 0, stream>>>(counts, offsets, cursor, NFIL);
    scatter_kernel<<<(E + 255) / 256, 256, 0, stream>>>(src, dst, cursor, csr_src, E);

    // --- fused edge softmax + aggregation, single gather (bf16 out) ---
    agg_kernel<<<NFIL, 256, 0, stream>>>(offsets, csr_src, el, er, embB, aggB, NFIL);

    // --- final fused GEMM (bf16 MFMA): out = aggB @ MmatT^T + bz ---
    gemm_mfma<<<dim3(2, (NFIL + 127) / 128), 256, 0, stream>>>(
        aggB, MmatT, bz, out, NFIL);
}